// Round 16
// baseline (1104.821 us; speedup 1.0000x reference)
//
#include <hip/hip_runtime.h>

#define N_TOK 65536
#define DIM   256
#define KCB   1024
#define LVL   8
#define TPB   32                  // tokens per block
#define THREADS 1024              // 16 waves
#define CAP   6                   // per-(wave,token) candidate slots
#define MARGIN_STAR 0.6f          // 1-pass hi-only: >= 2x f32/bf16 error bound (validated R6-R15)
#define MARGIN_F32  0.125f        // fallback path
#define RPAD  258                 // fallback r64 row stride

typedef __attribute__((ext_vector_type(8))) short bf16x8;
typedef __attribute__((ext_vector_type(4))) float f32x4;

static __device__ inline unsigned short f2bf(float f) {
    unsigned u = __float_as_uint(f);
    unsigned r = u + 0x7FFFu + ((u >> 16) & 1u);   // RNE
    return (unsigned short)(r >> 16);
}

// Exact f64 ||r - c||^2 (fallback path only). __noinline__: single instance.
__device__ __noinline__ double dist64(const double* r, const float* crow) {
    double s0 = 0.0, s1 = 0.0, s2 = 0.0, s3 = 0.0;
    #pragma unroll 8
    for (int d = 0; d < DIM; d += 4) {
        float4 c = *(const float4*)(crow + d);
        double a = r[d]     - (double)c.x;
        double b = r[d + 1] - (double)c.y;
        double e = r[d + 2] - (double)c.z;
        double f = r[d + 3] - (double)c.w;
        s0 += a * a; s1 += b * b; s2 += e * e; s3 += f * f;
    }
    return (s0 + s1) + (s2 + s3);
}

// ---- pack: codebook -> B-fragment-linear bf16 (hi only), 1KB per frag ----
// frag f = (l*64 + N)*8 + kk ; value(lane, j) = cb[l][N*16+(lane&15)][kk*32+(lane>>4)*8+j]
__global__ void pack_kernel(const float* __restrict__ cb, short* __restrict__ packed) {
    const int lane = threadIdx.x & 63;
    const int fid  = (blockIdx.x * blockDim.x + threadIdx.x) >> 6;  // 0..4095
    const int l  = fid >> 9;
    const int n  = (fid >> 3) & 63;
    const int kk = fid & 7;
    const int col = n * 16 + (lane & 15);
    const int kb  = kk * 32 + (lane >> 4) * 8;
    const float* src = cb + ((long)(l * KCB + col)) * DIM + kb;
    float4 f0 = *(const float4*)src;
    float4 f1 = *(const float4*)(src + 4);
    float fv[8] = {f0.x, f0.y, f0.z, f0.w, f1.x, f1.y, f1.z, f1.w};
    union { unsigned short s[8]; int4 v; } H;
    #pragma unroll
    for (int j = 0; j < 8; j++) H.s[j] = f2bf(fv[j]);
    *(int4*)(packed + (long)fid * 512 + lane * 8) = H.v;
}

// bias[l*K + k] = -0.5 * ||cb[l][k]||^2
__global__ void bias_kernel(const float* __restrict__ cb, float* __restrict__ bias) {
    const int lane = threadIdx.x & 63;
    const int wid  = (blockIdx.x * blockDim.x + threadIdx.x) >> 6;
    const int nw   = (gridDim.x * blockDim.x) >> 6;
    for (int row = wid; row < LVL * KCB; row += nw) {
        float4 c = *(const float4*)(cb + (long)row * DIM + lane * 4);
        float s = c.x * c.x + c.y * c.y + c.z * c.z + c.w * c.w;
        for (int off = 32; off; off >>= 1) s += __shfl_xor(s, off);
        if (lane == 0) bias[row] = -0.5f * s;
    }
}

// -------- main: 16-wave, 32-token tile, 1-pass hi-only, residual-in-registers --------
// 2 barriers/level: per-wave candidate lists (wavemax-margin superset) replace the
// {atomicMax -> barrier -> scan} round. Refine gathers lists, computes block max,
// filters to margin set, f64-refines. Overflow (>CAP, P~1e-9) -> full exact scan.
__global__ __launch_bounds__(THREADS, 4) void rvq_mfma(const float* __restrict__ x,
                                                       const float* __restrict__ cb,
                                                       const short* __restrict__ packed,
                                                       const float* __restrict__ bias,
                                                       float* __restrict__ out) {
    __shared__ short              abufH[2 * 8 * 64 * 8];   // 16 KB A-frags hi [m][kk][ls][j]
    __shared__ float              bias_s[KCB];             // 4 KB
    __shared__ int                cntw[16][TPB];           // 2 KB per-(wave,token) counts
    __shared__ unsigned long long listw[16][TPB][CAP];     // 24 KB (score_bits<<32 | k)
    __shared__ int                codes_s[TPB][LVL];       // 1 KB

    const int tid  = threadIdx.x;
    const int w    = tid >> 6;            // wave 0..15 -> cols [w*64, w*64+64)
    const int lane = tid & 63;
    const int tokq = tid >> 5;            // token 0..31 (32-thread group)
    const int c32  = tid & 31;
    const long tok0 = (long)blockIdx.x * TPB;
    const float* xblk = x + tok0 * DIM;

    // residual in registers: dims d = 2*c32 + 64*p + {0,1}, p = 0..3
    double res[8];
    #pragma unroll
    for (int p = 0; p < 4; p++) {
        float2 xv = *(const float2*)(xblk + tokq * DIM + 2 * c32 + 64 * p);
        res[2 * p]     = (double)xv.x;
        res[2 * p + 1] = (double)xv.y;
    }
    if (tid < 512) cntw[tid >> 5][tid & 31] = 0;
    bias_s[tid] = bias[tid];              // level-0 bias

    // A-convert for level 0
    {
        const int m = tokq >> 4, tr = tokq & 15;
        #pragma unroll
        for (int p = 0; p < 4; p++) {
            int d = 2 * c32 + 64 * p;
            unsigned short hA = f2bf((float)res[2 * p]);
            unsigned short hB = f2bf((float)res[2 * p + 1]);
            int kk  = d >> 5;
            int ls  = tr + ((d >> 3) & 3) * 16;
            int idx = ((m * 8 + kk) * 64 + ls) * 8 + (d & 7);   // even -> 4B aligned
            *(unsigned*)&abufH[idx] = (unsigned)hA | ((unsigned)hB << 16);
        }
    }
    __syncthreads();   // preloop: abufH/bias/counters ready

    for (int l = 0; l < LVL; l++) {
        const float* cbl = cb + (long)l * KCB * DIM;

        // ---- phase G: GEMM score* = r.c - 0.5||c||^2 (1-pass bf16-hi, depth-2 B pipe) ----
        const short* packW = packed + ((long)(l * 64 + w * 4) * 8) * 512 + lane * 8;
        bf16x8 chA[4], chB[4];
        #pragma unroll
        for (int n = 0; n < 4; n++) chA[n] = *(const bf16x8*)(packW + (long)(n * 8 + 0) * 512);
        #pragma unroll
        for (int n = 0; n < 4; n++) chB[n] = *(const bf16x8*)(packW + (long)(n * 8 + 1) * 512);
        f32x4 acc[2][4];                      // [m][n]
        #pragma unroll
        for (int n = 0; n < 4; n++) {
            float b = bias_s[w * 64 + n * 16 + (lane & 15)];
            acc[0][n] = (f32x4){b, b, b, b};
            acc[1][n] = (f32x4){b, b, b, b};
        }
        #pragma unroll
        for (int kk2 = 0; kk2 < 8; kk2 += 2) {
            {
                bf16x8 ah0 = *(const bf16x8*)(abufH + (kk2)     * 512 + lane * 8);
                bf16x8 ah1 = *(const bf16x8*)(abufH + (8 + kk2) * 512 + lane * 8);
                #pragma unroll
                for (int n = 0; n < 4; n++) {
                    acc[0][n] = __builtin_amdgcn_mfma_f32_16x16x32_bf16(ah0, chA[n], acc[0][n], 0, 0, 0);
                    acc[1][n] = __builtin_amdgcn_mfma_f32_16x16x32_bf16(ah1, chA[n], acc[1][n], 0, 0, 0);
                }
            }
            if (kk2 + 2 < 8) {
                #pragma unroll
                for (int n = 0; n < 4; n++)
                    chA[n] = *(const bf16x8*)(packW + (long)(n * 8 + kk2 + 2) * 512);
            }
            {
                bf16x8 ah0 = *(const bf16x8*)(abufH + (kk2 + 1) * 512 + lane * 8);
                bf16x8 ah1 = *(const bf16x8*)(abufH + (9 + kk2) * 512 + lane * 8);
                #pragma unroll
                for (int n = 0; n < 4; n++) {
                    acc[0][n] = __builtin_amdgcn_mfma_f32_16x16x32_bf16(ah0, chB[n], acc[0][n], 0, 0, 0);
                    acc[1][n] = __builtin_amdgcn_mfma_f32_16x16x32_bf16(ah1, chB[n], acc[1][n], 0, 0, 0);
                }
            }
            if (kk2 + 3 < 8) {
                #pragma unroll
                for (int n = 0; n < 4; n++)
                    chB[n] = *(const bf16x8*)(packW + (long)(n * 8 + kk2 + 3) * 512);
            }
        }

        // ---- wave max per token (shuffle) + wave-local candidate scan ----
        {
            float bv[2][4];
            #pragma unroll
            for (int m = 0; m < 2; m++)
                #pragma unroll
                for (int r = 0; r < 4; r++) {
                    float v = acc[m][0][r];
                    #pragma unroll
                    for (int n = 1; n < 4; n++) v = fmaxf(v, acc[m][n][r]);
                    bv[m][r] = v;
                }
            #pragma unroll
            for (int off = 1; off < 16; off <<= 1)
                #pragma unroll
                for (int m = 0; m < 2; m++)
                    #pragma unroll
                    for (int r = 0; r < 4; r++)
                        bv[m][r] = fmaxf(bv[m][r], __shfl_xor(bv[m][r], off));
            // candidates: score >= wavemax - MARGIN (superset of block-margin set)
            #pragma unroll
            for (int m = 0; m < 2; m++)
                #pragma unroll
                for (int r = 0; r < 4; r++) {
                    int tok = m * 16 + (lane >> 4) * 4 + r;
                    float thr = bv[m][r] - MARGIN_STAR;
                    #pragma unroll
                    for (int n = 0; n < 4; n++) {
                        if (acc[m][n][r] >= thr) {
                            int k = w * 64 + n * 16 + (lane & 15);
                            int pos = atomicAdd(&cntw[w][tok], 1);
                            if (pos < CAP)
                                listw[w][tok][pos] =
                                    ((unsigned long long)__float_as_uint(acc[m][n][r]) << 32) | (unsigned)k;
                        }
                    }
                }
        }
        __syncthreads();   // ---- barrier 1: all wave lists published ----

        // ---- phase R: gather lists, block max, filter, exact-f64 refine, update ----
        int rawc = (c32 < 16) ? cntw[c32][tokq] : 0;
        int cc   = rawc > CAP ? CAP : rawc;
        if (c32 < 16) cntw[c32][tokq] = 0;        // reset for next level (reads done)
        // pack clamped counts (3 bits x 16) into a u64 every thread holds
        unsigned long long cnts = 0;
        #pragma unroll
        for (int i = 0; i < 16; i++) {
            int ci = __shfl(cc, i, 32);
            cnts |= (unsigned long long)(ci & 7) << (3 * i);
        }
        int ov = (rawc > CAP) ? 1 : 0;
        #pragma unroll
        for (int off = 1; off < 32; off <<= 1) ov |= __shfl_xor(ov, off);
        int total = 0;
        #pragma unroll
        for (int i = 0; i < 16; i++) total += (int)((cnts >> (3 * i)) & 7);

        int bk;
        if (ov) {
            // overflow (P ~ 1e-9): full exact f64 argmin over all 1024 cols
            double bd = 1e300; bk = KCB;
            for (int k = 0; k < KCB; k++) {
                const float* crow = cbl + (long)k * DIM + 2 * c32;
                double s = 0.0;
                #pragma unroll
                for (int p = 0; p < 4; p++) {
                    float2 cv = *(const float2*)(crow + 64 * p);
                    double a  = res[2 * p]     - (double)cv.x;
                    double b2 = res[2 * p + 1] - (double)cv.y;
                    s += a * a + b2 * b2;
                }
                #pragma unroll
                for (int off = 1; off < 32; off <<= 1) s += __shfl_xor(s, off);
                if (s < bd) { bd = s; bk = k; }    // ascending k => lowest-k tie-break
            }
        } else if (total == 1) {
            bk = KCB;
            for (int wv = 0; wv < 16; wv++)
                if ((cnts >> (3 * wv)) & 7) { bk = (int)(listw[wv][tokq][0] & 0xFFFFFFFFu); break; }
        } else {
            // block max over stored scores
            float lmax = -1e30f;
            if (c32 < 16)
                for (int j = 0; j < cc; j++)
                    lmax = fmaxf(lmax, __uint_as_float((unsigned)(listw[c32][tokq][j] >> 32)));
            #pragma unroll
            for (int off = 1; off < 32; off <<= 1) lmax = fmaxf(lmax, __shfl_xor(lmax, off));
            float thr = lmax - MARGIN_STAR;
            double bd = 1e300; bk = KCB;
            for (int wv = 0; wv < 16; wv++) {
                int cw = (int)((cnts >> (3 * wv)) & 7);
                for (int j = 0; j < cw; j++) {
                    unsigned long long e = listw[wv][tokq][j];
                    float sc = __uint_as_float((unsigned)(e >> 32));
                    if (sc >= thr) {
                        int k = (int)(e & 0xFFFFFFFFu);
                        const float* crow = cbl + (long)k * DIM + 2 * c32;
                        double s = 0.0;
                        #pragma unroll
                        for (int p = 0; p < 4; p++) {
                            float2 cv = *(const float2*)(crow + 64 * p);
                            double a  = res[2 * p]     - (double)cv.x;
                            double b2 = res[2 * p + 1] - (double)cv.y;
                            s += a * a + b2 * b2;
                        }
                        #pragma unroll
                        for (int off = 1; off < 32; off <<= 1) s += __shfl_xor(s, off);
                        if (s < bd || (s == bd && k < bk)) { bd = s; bk = k; }
                    }
                }
            }
        }
        if (c32 == 0) codes_s[tokq][l] = bk;

        // residual update + fused A-convert for l+1 + bias prefetch
        if (l + 1 < LVL) bias_s[tid] = bias[(l + 1) * KCB + tid];
        {
            const float* crow = cbl + (long)bk * DIM + 2 * c32;
            const int m = tokq >> 4, tr = tokq & 15;
            #pragma unroll
            for (int p = 0; p < 4; p++) {
                float2 cv = *(const float2*)(crow + 64 * p);
                res[2 * p]     -= (double)cv.x;
                res[2 * p + 1] -= (double)cv.y;
                if (l + 1 < LVL) {
                    int d = 2 * c32 + 64 * p;
                    unsigned short hA = f2bf((float)res[2 * p]);
                    unsigned short hB = f2bf((float)res[2 * p + 1]);
                    int kk  = d >> 5;
                    int ls  = tr + ((d >> 3) & 3) * 16;
                    int idx = ((m * 8 + kk) * 64 + ls) * 8 + (d & 7);
                    *(unsigned*)&abufH[idx] = (unsigned)hA | ((unsigned)hB << 16);
                }
            }
        }
        __syncthreads();   // ---- barrier 2: abufH/bias/counters ready for l+1 ----
    }

    // ---- outputs: quantized = x - residual ; codes as float ----
    #pragma unroll
    for (int p = 0; p < 4; p++) {
        int d = 2 * c32 + 64 * p;
        float2 xv = *(const float2*)(xblk + tokq * DIM + d);
        float2 q;
        q.x = (float)((double)xv.x - res[2 * p]);
        q.y = (float)((double)xv.y - res[2 * p + 1]);
        *(float2*)(out + (tok0 + tokq) * DIM + d) = q;
    }
    float* cout = out + (long)N_TOK * DIM;
    if (tid < TPB * LVL) {
        int t = tid >> 3, ll = tid & 7;
        cout[(tok0 + t) * LVL + ll] = (float)codes_s[t][ll];
    }
}

// ================= fallback (f32 path, needs only 32KB ws) =================
__global__ void csq_kernel(const float* __restrict__ cb, float* __restrict__ csq) {
    const int lane = threadIdx.x & 63;
    const int wid  = (blockIdx.x * blockDim.x + threadIdx.x) >> 6;
    const int nw   = (gridDim.x * blockDim.x) >> 6;
    for (int row = wid; row < LVL * KCB; row += nw) {
        float4 c = *(const float4*)(cb + (long)row * DIM + lane * 4);
        float s = c.x * c.x + c.y * c.y + c.z * c.z + c.w * c.w;
        for (int off = 32; off; off >>= 1) s += __shfl_xor(s, off);
        if (lane == 0) csq[row] = s;
    }
}

__global__ __launch_bounds__(256) void rvq_kernel(const float* __restrict__ x,
                                                  const float* __restrict__ cb,
                                                  const float* __restrict__ csq,
                                                  float* __restrict__ out) {
    __shared__ double r64[16 * RPAD];
    __shared__ float  r32[16 * DIM];
    __shared__ float  wval[4][16];
    __shared__ float  minv[16];
    __shared__ unsigned long long dbits[16];
    __shared__ int    dmin_idx[16];
    __shared__ int    codes_s2[16][LVL];

    const int tid  = threadIdx.x;
    const int wave = tid >> 6;
    const int lane = tid & 63;
    const long tok0 = (long)blockIdx.x * 16;
    const float* xblk = x + tok0 * DIM;

    for (int i = 0; i < 16; i++) {
        float v = xblk[i * DIM + tid];
        r64[i * RPAD + tid] = (double)v;
        r32[i * DIM + tid] = v;
    }
    __syncthreads();

    const int k0 = wave * 256 + lane * 4;
    for (int l = 0; l < LVL; l++) {
        const float* cbl = cb + (long)l * KCB * DIM;
        float acc[4][16];
        #pragma unroll
        for (int j = 0; j < 4; j++)
            #pragma unroll
            for (int t = 0; t < 16; t++) acc[j][t] = 0.f;
        for (int d0 = 0; d0 < DIM; d0 += 4) {
            float4 c4[4];
            #pragma unroll
            for (int j = 0; j < 4; j++)
                c4[j] = *(const float4*)(cbl + (long)(k0 + j) * DIM + d0);
            #pragma unroll
            for (int t = 0; t < 16; t++) {
                float4 r4 = *(const float4*)(r32 + t * DIM + d0);
                #pragma unroll
                for (int j = 0; j < 4; j++) {
                    acc[j][t] = fmaf(c4[j].x, r4.x, acc[j][t]);
                    acc[j][t] = fmaf(c4[j].y, r4.y, acc[j][t]);
                    acc[j][t] = fmaf(c4[j].z, r4.z, acc[j][t]);
                    acc[j][t] = fmaf(c4[j].w, r4.w, acc[j][t]);
                }
            }
        }
        float cs[4];
        #pragma unroll
        for (int j = 0; j < 4; j++) cs[j] = csq[l * KCB + k0 + j];
        #pragma unroll
        for (int j = 0; j < 4; j++)
            #pragma unroll
            for (int t = 0; t < 16; t++)
                acc[j][t] = cs[j] - 2.0f * acc[j][t];

        #pragma unroll
        for (int t = 0; t < 16; t++) {
            float bv = acc[0][t];
            #pragma unroll
            for (int j = 1; j < 4; j++) bv = fminf(bv, acc[j][t]);
            for (int off = 1; off < 64; off <<= 1) bv = fminf(bv, __shfl_xor(bv, off));
            if (lane == 0) wval[wave][t] = bv;
        }
        __syncthreads();
        if (tid < 16) {
            float m = wval[0][tid];
            for (int ww = 1; ww < 4; ww++) m = fminf(m, wval[ww][tid]);
            minv[tid] = m;
            dbits[tid] = 0xFFFFFFFFFFFFFFFFULL;
            dmin_idx[tid] = KCB;
        }
        __syncthreads();
        #pragma unroll
        for (int t = 0; t < 16; t++) {
            float thr = minv[t] + MARGIN_F32;
            #pragma unroll
            for (int j = 0; j < 4; j++)
                if (acc[j][t] <= thr) {
                    double d64 = dist64(r64 + t * RPAD, cbl + (long)(k0 + j) * DIM);
                    atomicMin(&dbits[t], (unsigned long long)__double_as_longlong(d64));
                }
        }
        __syncthreads();
        #pragma unroll
        for (int t = 0; t < 16; t++) {
            float thr = minv[t] + MARGIN_F32;
            #pragma unroll
            for (int j = 0; j < 4; j++)
                if (acc[j][t] <= thr) {
                    double d64 = dist64(r64 + t * RPAD, cbl + (long)(k0 + j) * DIM);
                    if ((unsigned long long)__double_as_longlong(d64) == dbits[t])
                        atomicMin(&dmin_idx[t], k0 + j);
                }
        }
        __syncthreads();
        if (tid < 16) codes_s2[tid][l] = dmin_idx[tid];
        for (int i = 0; i < 16; i++) {
            int k = dmin_idx[i];
            float c = cbl[(long)k * DIM + tid];
            double nr = r64[i * RPAD + tid] - (double)c;
            r64[i * RPAD + tid] = nr;
            r32[i * DIM + tid] = (float)nr;
        }
        __syncthreads();
    }
    for (int i = 0; i < 16; i++) {
        double q = (double)xblk[i * DIM + tid] - r64[i * RPAD + tid];
        out[tok0 * DIM + i * DIM + tid] = (float)q;
    }
    float* cout = out + (long)N_TOK * DIM;
    if (tid < 16 * LVL) {
        int t = tid >> 3, ll = tid & 7;
        cout[(tok0 + t) * LVL + ll] = (float)codes_s2[t][ll];
    }
}

extern "C" void kernel_launch(void* const* d_in, const int* in_sizes, int n_in,
                              void* d_out, int out_size, void* d_ws, size_t ws_size,
                              hipStream_t stream) {
    const float* x  = (const float*)d_in[0];
    const float* cb = (const float*)d_in[1];
    const size_t need = (size_t)4 * 1024 * 1024 + 32 * 1024;
    if (ws_size >= need) {
        short* packed = (short*)d_ws;
        float* bias = (float*)((char*)d_ws + (size_t)4 * 1024 * 1024);
        pack_kernel<<<1024, 256, 0, stream>>>(cb, packed);
        bias_kernel<<<32, 256, 0, stream>>>(cb, bias);
        rvq_mfma<<<N_TOK / TPB, THREADS, 0, stream>>>(x, cb, packed, bias, (float*)d_out);
    } else {
        float* csq = (float*)d_ws;
        csq_kernel<<<32, 256, 0, stream>>>(cb, csq);
        rvq_kernel<<<N_TOK / 16, 256, 0, stream>>>(x, cb, csq, (float*)d_out);
    }
}

// Round 17
// 655.120 us; speedup vs baseline: 1.6864x; 1.6864x over previous
//
#include <hip/hip_runtime.h>

#define N_TOK 65536
#define DIM   256
#define KCB   1024
#define LVL   8
#define TPB   32                  // tokens per block
#define THREADS 1024              // 16 waves
#define CAND_MAX 32
#define MARGIN_STAR 0.6f          // 1-pass hi-only: ~13 sigma of bf16 error (validated R6-R16)
#define MARGIN_F32  0.125f        // fallback path
#define RPAD  258                 // fallback r64 row stride

typedef __attribute__((ext_vector_type(8))) short bf16x8;
typedef __attribute__((ext_vector_type(4))) float f32x4;

static __device__ inline unsigned short f2bf(float f) {
    unsigned u = __float_as_uint(f);
    unsigned r = u + 0x7FFFu + ((u >> 16) & 1u);   // RNE
    return (unsigned short)(r >> 16);
}

// order-preserving f32 <-> u32 (for LDS atomicMax on scores, incl. negatives)
static __device__ inline unsigned fflip(float x) {
    unsigned u = __float_as_uint(x);
    return (u & 0x80000000u) ? ~u : (u | 0x80000000u);
}
static __device__ inline float funflip(unsigned u) {
    return __uint_as_float((u & 0x80000000u) ? (u & 0x7FFFFFFFu) : ~u);
}

// Exact f64 ||r - c||^2 (fallback path only). __noinline__: single instance.
__device__ __noinline__ double dist64(const double* r, const float* crow) {
    double s0 = 0.0, s1 = 0.0, s2 = 0.0, s3 = 0.0;
    #pragma unroll 8
    for (int d = 0; d < DIM; d += 4) {
        float4 c = *(const float4*)(crow + d);
        double a = r[d]     - (double)c.x;
        double b = r[d + 1] - (double)c.y;
        double e = r[d + 2] - (double)c.z;
        double f = r[d + 3] - (double)c.w;
        s0 += a * a; s1 += b * b; s2 += e * e; s3 += f * f;
    }
    return (s0 + s1) + (s2 + s3);
}

// ---- pack: codebook -> B-fragment-linear bf16 (hi only), 1KB per frag ----
// frag f = (l*64 + N)*8 + kk ; value(lane, j) = cb[l][N*16+(lane&15)][kk*32+(lane>>4)*8+j]
__global__ void pack_kernel(const float* __restrict__ cb, short* __restrict__ packed) {
    const int lane = threadIdx.x & 63;
    const int fid  = (blockIdx.x * blockDim.x + threadIdx.x) >> 6;  // 0..4095
    const int l  = fid >> 9;
    const int n  = (fid >> 3) & 63;
    const int kk = fid & 7;
    const int col = n * 16 + (lane & 15);
    const int kb  = kk * 32 + (lane >> 4) * 8;
    const float* src = cb + ((long)(l * KCB + col)) * DIM + kb;
    float4 f0 = *(const float4*)src;
    float4 f1 = *(const float4*)(src + 4);
    float fv[8] = {f0.x, f0.y, f0.z, f0.w, f1.x, f1.y, f1.z, f1.w};
    union { unsigned short s[8]; int4 v; } H;
    #pragma unroll
    for (int j = 0; j < 8; j++) H.s[j] = f2bf(fv[j]);
    *(int4*)(packed + (long)fid * 512 + lane * 8) = H.v;
}

// bias[l*K + k] = -0.5 * ||cb[l][k]||^2
__global__ void bias_kernel(const float* __restrict__ cb, float* __restrict__ bias) {
    const int lane = threadIdx.x & 63;
    const int wid  = (blockIdx.x * blockDim.x + threadIdx.x) >> 6;
    const int nw   = (gridDim.x * blockDim.x) >> 6;
    for (int row = wid; row < LVL * KCB; row += nw) {
        float4 c = *(const float4*)(cb + (long)row * DIM + lane * 4);
        float s = c.x * c.x + c.y * c.y + c.z * c.z + c.w * c.w;
        for (int off = 32; off; off >>= 1) s += __shfl_xor(s, off);
        if (lane == 0) bias[row] = -0.5f * s;
    }
}

// -------- main: 16-wave, 32-token tile, 1-pass hi-only, residual-in-registers --------
// R9 register plan (proven no-spill) + B-loads hoisted before barrier 1 +
// atomicMax block max (one fewer barrier) + bias staging moved off the critical path.
__global__ __launch_bounds__(THREADS, 4) void rvq_mfma(const float* __restrict__ x,
                                                       const float* __restrict__ cb,
                                                       const short* __restrict__ packed,
                                                       const float* __restrict__ bias,
                                                       float* __restrict__ out) {
    __shared__ short    abufH[2 * 8 * 64 * 8];   // 16 KB A-frags hi  [m][kk][ls][j]
    __shared__ float    bias_s[KCB];             // 4 KB
    __shared__ unsigned maxu[TPB];               // block max (flipped f32)
    __shared__ int      ccnt[TPB];
    __shared__ int      clist[TPB][CAND_MAX];    // 4 KB
    __shared__ int      codes_s[TPB][LVL];       // 1 KB

    const int tid  = threadIdx.x;
    const int w    = tid >> 6;            // wave 0..15 -> cols [w*64, w*64+64)
    const int lane = tid & 63;
    const int tokq = tid >> 5;            // token 0..31 (32-thread group)
    const int c32  = tid & 31;
    const long tok0 = (long)blockIdx.x * TPB;
    const float* xblk = x + tok0 * DIM;

    // residual in registers: dims d = 2*c32 + 64*p + {0,1}, p = 0..3
    double res[8];
    #pragma unroll
    for (int p = 0; p < 4; p++) {
        float2 xv = *(const float2*)(xblk + tokq * DIM + 2 * c32 + 64 * p);
        res[2 * p]     = (double)xv.x;
        res[2 * p + 1] = (double)xv.y;
    }
    if (tid < TPB) { ccnt[tid] = 0; maxu[tid] = 0u; }
    bias_s[tid] = bias[tid];              // level-0 bias

    for (int l = 0; l < LVL; l++) {
        const float* cbl = cb + (long)l * KCB * DIM;

        // ---- phase 1: issue B-loads (kk=0,1) early, then A-convert ----
        const short* packW = packed + ((long)(l * 64 + w * 4) * 8) * 512 + lane * 8;
        bf16x8 chA[4], chB[4];
        #pragma unroll
        for (int n = 0; n < 4; n++) chA[n] = *(const bf16x8*)(packW + (long)(n * 8 + 0) * 512);
        #pragma unroll
        for (int n = 0; n < 4; n++) chB[n] = *(const bf16x8*)(packW + (long)(n * 8 + 1) * 512);
        {
            const int m = tokq >> 4, tr = tokq & 15;
            #pragma unroll
            for (int p = 0; p < 4; p++) {
                int d = 2 * c32 + 64 * p;
                unsigned short hA = f2bf((float)res[2 * p]);
                unsigned short hB = f2bf((float)res[2 * p + 1]);
                int kk  = d >> 5;
                int ls  = tr + ((d >> 3) & 3) * 16;
                int idx = ((m * 8 + kk) * 64 + ls) * 8 + (d & 7);   // even -> 4B aligned
                *(unsigned*)&abufH[idx] = (unsigned)hA | ((unsigned)hB << 16);
            }
        }
        __syncthreads();   // ---- barrier 1: abufH ready (B-loads in flight) ----

        // ---- phase 2: GEMM score* = r.c - 0.5||c||^2 (1-pass bf16-hi, depth-2 B pipe) ----
        f32x4 acc[2][4];                      // [m][n]
        #pragma unroll
        for (int n = 0; n < 4; n++) {
            float b = bias_s[w * 64 + n * 16 + (lane & 15)];
            acc[0][n] = (f32x4){b, b, b, b};
            acc[1][n] = (f32x4){b, b, b, b};
        }
        #pragma unroll
        for (int kk2 = 0; kk2 < 8; kk2 += 2) {
            {
                bf16x8 ah0 = *(const bf16x8*)(abufH + (kk2)     * 512 + lane * 8);
                bf16x8 ah1 = *(const bf16x8*)(abufH + (8 + kk2) * 512 + lane * 8);
                #pragma unroll
                for (int n = 0; n < 4; n++) {
                    acc[0][n] = __builtin_amdgcn_mfma_f32_16x16x32_bf16(ah0, chA[n], acc[0][n], 0, 0, 0);
                    acc[1][n] = __builtin_amdgcn_mfma_f32_16x16x32_bf16(ah1, chA[n], acc[1][n], 0, 0, 0);
                }
            }
            if (kk2 + 2 < 8) {
                #pragma unroll
                for (int n = 0; n < 4; n++)
                    chA[n] = *(const bf16x8*)(packW + (long)(n * 8 + kk2 + 2) * 512);
            }
            {
                bf16x8 ah0 = *(const bf16x8*)(abufH + (kk2 + 1) * 512 + lane * 8);
                bf16x8 ah1 = *(const bf16x8*)(abufH + (9 + kk2) * 512 + lane * 8);
                #pragma unroll
                for (int n = 0; n < 4; n++) {
                    acc[0][n] = __builtin_amdgcn_mfma_f32_16x16x32_bf16(ah0, chB[n], acc[0][n], 0, 0, 0);
                    acc[1][n] = __builtin_amdgcn_mfma_f32_16x16x32_bf16(ah1, chB[n], acc[1][n], 0, 0, 0);
                }
            }
            if (kk2 + 3 < 8) {
                #pragma unroll
                for (int n = 0; n < 4; n++)
                    chB[n] = *(const bf16x8*)(packW + (long)(n * 8 + kk2 + 3) * 512);
            }
        }

        // ---- wave-level per-token max -> block max via LDS atomicMax ----
        {
            float bv[2][4];
            #pragma unroll
            for (int m = 0; m < 2; m++)
                #pragma unroll
                for (int r = 0; r < 4; r++) {
                    float v = acc[m][0][r];
                    #pragma unroll
                    for (int n = 1; n < 4; n++) v = fmaxf(v, acc[m][n][r]);
                    bv[m][r] = v;
                }
            #pragma unroll
            for (int off = 1; off < 16; off <<= 1)
                #pragma unroll
                for (int m = 0; m < 2; m++)
                    #pragma unroll
                    for (int r = 0; r < 4; r++)
                        bv[m][r] = fmaxf(bv[m][r], __shfl_xor(bv[m][r], off));
            if ((lane & 15) == 0)
                #pragma unroll
                for (int m = 0; m < 2; m++)
                    #pragma unroll
                    for (int r = 0; r < 4; r++)
                        atomicMax(&maxu[m * 16 + (lane >> 4) * 4 + r], fflip(bv[m][r]));
        }
        __syncthreads();   // ---- barrier 2: block max ready ----

        // ---- phase 3: candidate scan -> per-token LDS lists ----
        #pragma unroll
        for (int m = 0; m < 2; m++)
            #pragma unroll
            for (int r = 0; r < 4; r++) {
                int tok = m * 16 + (lane >> 4) * 4 + r;
                float thr = funflip(maxu[tok]) - MARGIN_STAR;
                #pragma unroll
                for (int n = 0; n < 4; n++) {
                    if (acc[m][n][r] >= thr) {
                        int k = w * 64 + n * 16 + (lane & 15);
                        int pos = atomicAdd(&ccnt[tok], 1);
                        if (pos < CAND_MAX) clist[tok][pos] = k;
                    }
                }
            }
        __syncthreads();   // ---- barrier 3: lists complete ----

        // ---- phase 4: cooperative exact-f64 refine (32 threads/token) + update ----
        int cnt = ccnt[tokq];
        if (cnt > CAND_MAX) cnt = CAND_MAX;
        if (c32 == 0) { ccnt[tokq] = 0; maxu[tokq] = 0u; }   // reset (next use after bar1/bar2 of l+1)
        if (l + 1 < LVL) bias_s[tid] = bias[(l + 1) * KCB + tid];  // latency hides under refine
        int bk;
        if (cnt == 1) {
            bk = clist[tokq][0];             // singleton set => true argmin
        } else {
            double bd = 1e300; bk = KCB;
            for (int j = 0; j < cnt; j++) {
                int k = clist[tokq][j];
                const float* crow = cbl + (long)k * DIM + 2 * c32;
                double s = 0.0;
                #pragma unroll
                for (int p = 0; p < 4; p++) {
                    float2 cv = *(const float2*)(crow + 64 * p);
                    double a  = res[2 * p]     - (double)cv.x;
                    double b2 = res[2 * p + 1] - (double)cv.y;
                    s += a * a + b2 * b2;
                }
                #pragma unroll
                for (int off = 1; off < 32; off <<= 1) s += __shfl_xor(s, off);
                if (s < bd || (s == bd && k < bk)) { bd = s; bk = k; }
            }
        }
        if (c32 == 0) codes_s[tokq][l] = bk;
        {
            const float* crow = cbl + (long)bk * DIM + 2 * c32;
            #pragma unroll
            for (int p = 0; p < 4; p++) {
                float2 cv = *(const float2*)(crow + 64 * p);
                res[2 * p]     -= (double)cv.x;
                res[2 * p + 1] -= (double)cv.y;
            }
        }
        // no barrier: next level's abufH writes are separated from this level's
        // readers by barrier 1 of the next iteration.
    }
    __syncthreads();       // codes_s complete before output remap

    // ---- outputs: quantized = x - residual ; codes as float ----
    #pragma unroll
    for (int p = 0; p < 4; p++) {
        int d = 2 * c32 + 64 * p;
        float2 xv = *(const float2*)(xblk + tokq * DIM + d);
        float2 q;
        q.x = (float)((double)xv.x - res[2 * p]);
        q.y = (float)((double)xv.y - res[2 * p + 1]);
        *(float2*)(out + (tok0 + tokq) * DIM + d) = q;
    }
    float* cout = out + (long)N_TOK * DIM;
    if (tid < TPB * LVL) {
        int t = tid >> 3, ll = tid & 7;
        cout[(tok0 + t) * LVL + ll] = (float)codes_s[t][ll];
    }
}

// ================= fallback (f32 path, needs only 32KB ws) =================
__global__ void csq_kernel(const float* __restrict__ cb, float* __restrict__ csq) {
    const int lane = threadIdx.x & 63;
    const int wid  = (blockIdx.x * blockDim.x + threadIdx.x) >> 6;
    const int nw   = (gridDim.x * blockDim.x) >> 6;
    for (int row = wid; row < LVL * KCB; row += nw) {
        float4 c = *(const float4*)(cb + (long)row * DIM + lane * 4);
        float s = c.x * c.x + c.y * c.y + c.z * c.z + c.w * c.w;
        for (int off = 32; off; off >>= 1) s += __shfl_xor(s, off);
        if (lane == 0) csq[row] = s;
    }
}

__global__ __launch_bounds__(256) void rvq_kernel(const float* __restrict__ x,
                                                  const float* __restrict__ cb,
                                                  const float* __restrict__ csq,
                                                  float* __restrict__ out) {
    __shared__ double r64[16 * RPAD];
    __shared__ float  r32[16 * DIM];
    __shared__ float  wval[4][16];
    __shared__ float  minv[16];
    __shared__ unsigned long long dbits[16];
    __shared__ int    dmin_idx[16];
    __shared__ int    codes_s2[16][LVL];

    const int tid  = threadIdx.x;
    const int wave = tid >> 6;
    const int lane = tid & 63;
    const long tok0 = (long)blockIdx.x * 16;
    const float* xblk = x + tok0 * DIM;

    for (int i = 0; i < 16; i++) {
        float v = xblk[i * DIM + tid];
        r64[i * RPAD + tid] = (double)v;
        r32[i * DIM + tid] = v;
    }
    __syncthreads();

    const int k0 = wave * 256 + lane * 4;
    for (int l = 0; l < LVL; l++) {
        const float* cbl = cb + (long)l * KCB * DIM;
        float acc[4][16];
        #pragma unroll
        for (int j = 0; j < 4; j++)
            #pragma unroll
            for (int t = 0; t < 16; t++) acc[j][t] = 0.f;
        for (int d0 = 0; d0 < DIM; d0 += 4) {
            float4 c4[4];
            #pragma unroll
            for (int j = 0; j < 4; j++)
                c4[j] = *(const float4*)(cbl + (long)(k0 + j) * DIM + d0);
            #pragma unroll
            for (int t = 0; t < 16; t++) {
                float4 r4 = *(const float4*)(r32 + t * DIM + d0);
                #pragma unroll
                for (int j = 0; j < 4; j++) {
                    acc[j][t] = fmaf(c4[j].x, r4.x, acc[j][t]);
                    acc[j][t] = fmaf(c4[j].y, r4.y, acc[j][t]);
                    acc[j][t] = fmaf(c4[j].z, r4.z, acc[j][t]);
                    acc[j][t] = fmaf(c4[j].w, r4.w, acc[j][t]);
                }
            }
        }
        float cs[4];
        #pragma unroll
        for (int j = 0; j < 4; j++) cs[j] = csq[l * KCB + k0 + j];
        #pragma unroll
        for (int j = 0; j < 4; j++)
            #pragma unroll
            for (int t = 0; t < 16; t++)
                acc[j][t] = cs[j] - 2.0f * acc[j][t];

        #pragma unroll
        for (int t = 0; t < 16; t++) {
            float bv = acc[0][t];
            #pragma unroll
            for (int j = 1; j < 4; j++) bv = fminf(bv, acc[j][t]);
            for (int off = 1; off < 64; off <<= 1) bv = fminf(bv, __shfl_xor(bv, off));
            if (lane == 0) wval[wave][t] = bv;
        }
        __syncthreads();
        if (tid < 16) {
            float m = wval[0][tid];
            for (int ww = 1; ww < 4; ww++) m = fminf(m, wval[ww][tid]);
            minv[tid] = m;
            dbits[tid] = 0xFFFFFFFFFFFFFFFFULL;
            dmin_idx[tid] = KCB;
        }
        __syncthreads();
        #pragma unroll
        for (int t = 0; t < 16; t++) {
            float thr = minv[t] + MARGIN_F32;
            #pragma unroll
            for (int j = 0; j < 4; j++)
                if (acc[j][t] <= thr) {
                    double d64 = dist64(r64 + t * RPAD, cbl + (long)(k0 + j) * DIM);
                    atomicMin(&dbits[t], (unsigned long long)__double_as_longlong(d64));
                }
        }
        __syncthreads();
        #pragma unroll
        for (int t = 0; t < 16; t++) {
            float thr = minv[t] + MARGIN_F32;
            #pragma unroll
            for (int j = 0; j < 4; j++)
                if (acc[j][t] <= thr) {
                    double d64 = dist64(r64 + t * RPAD, cbl + (long)(k0 + j) * DIM);
                    if ((unsigned long long)__double_as_longlong(d64) == dbits[t])
                        atomicMin(&dmin_idx[t], k0 + j);
                }
        }
        __syncthreads();
        if (tid < 16) codes_s2[tid][l] = dmin_idx[tid];
        for (int i = 0; i < 16; i++) {
            int k = dmin_idx[i];
            float c = cbl[(long)k * DIM + tid];
            double nr = r64[i * RPAD + tid] - (double)c;
            r64[i * RPAD + tid] = nr;
            r32[i * DIM + tid] = (float)nr;
        }
        __syncthreads();
    }
    for (int i = 0; i < 16; i++) {
        double q = (double)xblk[i * DIM + tid] - r64[i * RPAD + tid];
        out[tok0 * DIM + i * DIM + tid] = (float)q;
    }
    float* cout = out + (long)N_TOK * DIM;
    if (tid < 16 * LVL) {
        int t = tid >> 3, ll = tid & 7;
        cout[(tok0 + t) * LVL + ll] = (float)codes_s2[t][ll];
    }
}

extern "C" void kernel_launch(void* const* d_in, const int* in_sizes, int n_in,
                              void* d_out, int out_size, void* d_ws, size_t ws_size,
                              hipStream_t stream) {
    const float* x  = (const float*)d_in[0];
    const float* cb = (const float*)d_in[1];
    const size_t need = (size_t)4 * 1024 * 1024 + 32 * 1024;
    if (ws_size >= need) {
        short* packed = (short*)d_ws;
        float* bias = (float*)((char*)d_ws + (size_t)4 * 1024 * 1024);
        pack_kernel<<<1024, 256, 0, stream>>>(cb, packed);
        bias_kernel<<<32, 256, 0, stream>>>(cb, bias);
        rvq_mfma<<<N_TOK / TPB, THREADS, 0, stream>>>(x, cb, packed, bias, (float*)d_out);
    } else {
        float* csq = (float*)d_ws;
        csq_kernel<<<32, 256, 0, stream>>>(cb, csq);
        rvq_kernel<<<N_TOK / 16, 256, 0, stream>>>(x, cb, csq, (float*)d_out);
    }
}